// Round 2
// baseline (7845.927 us; speedup 1.0000x reference)
//
#include <hip/hip_runtime.h>

// LSTMFromEmbeddings: B=128, T=1024, E=256, H=256, C=2, bidirectional + meanpool + linear.
//
// Fused design (no xg precompute -> workspace ~516 KiB):
//  rec:  persistent 128 wgs = 16 groups (2 dir x 8 batch-blocks of 16) x 8 hidden-blocks
//        (32 units each). Per wg, LDS-resident bf16 slices of W_ih (64KB) and W_hh (64KB).
//        Per step: stage x_t (masked, ->bf16) + h_t into LDS, MFMA gates = x@Wi + h@Wh,
//        fp32 LSTM elementwise, publish h slice to global double buffer, group barrier
//        (atomic counter + explicit __threadfence release/acquire: correct for any XCD
//        placement; bid%16 grouping keeps members co-XCD for speed).
//  head: out = (hsum/1024) @ W_lin^T + b_lin.

#define B_ 128
#define T_ 1024
#define E_ 256
#define H_ 256
#define NGRP 16   // 2 dirs x 8 batch blocks
#define BB 16     // batches per group

typedef short short8 __attribute__((ext_vector_type(8)));
typedef float f32x4 __attribute__((ext_vector_type(4)));

__device__ __forceinline__ unsigned short f2bf(float f) {
  unsigned u = __builtin_bit_cast(unsigned, f);
  u += 0x7fffu + ((u >> 16) & 1u);  // RNE
  return (unsigned short)(u >> 16);
}
__device__ __forceinline__ f32x4 mfma16(short8 a, short8 b, f32x4 c) {
  return __builtin_amdgcn_mfma_f32_16x16x32_bf16(a, b, c, 0, 0, 0);
}
__device__ __forceinline__ float sigmf(float x) { return 1.0f / (1.0f + __expf(-x)); }

__device__ __forceinline__ short8 cvt8(f32x4 v0, f32x4 v1) {
  short8 o;
  o[0] = (short)f2bf(v0[0]); o[1] = (short)f2bf(v0[1]);
  o[2] = (short)f2bf(v0[2]); o[3] = (short)f2bf(v0[3]);
  o[4] = (short)f2bf(v1[0]); o[5] = (short)f2bf(v1[1]);
  o[6] = (short)f2bf(v1[2]); o[7] = (short)f2bf(v1[3]);
  return o;
}

// ---------------- rec: fused projection + recurrence -------------------------
// grid 128, 512 threads. g = bid & 15 (group), hb = bid >> 4 (hidden block).
__global__ __launch_bounds__(512, 1) void rec_kernel(
    const float* __restrict__ x, const float* __restrict__ mask,
    const float* __restrict__ WihF, const float* __restrict__ WhhF,
    const float* __restrict__ bF, const float* __restrict__ WihB,
    const float* __restrict__ WhhB, const float* __restrict__ bB,
    unsigned short* __restrict__ Hbuf, float* __restrict__ hsum,
    unsigned* __restrict__ flags) {
  __shared__ __align__(16) short WiL[128 * 256];  // W_ih slice bf16 swizzled (64KB)
  __shared__ __align__(16) short WhL[128 * 256];  // W_hh slice bf16 swizzled (64KB)
  __shared__ __align__(16) char UN[16384];        // [0,8K): x stage / gates, [8K,16K): h stage
  short* XS = (short*)UN;
  short* HS = (short*)(UN + 8192);
  float* gatesL = (float*)UN;

  int bid = blockIdx.x;
  int g = bid & 15, hb = bid >> 4;
  int d = g >> 3, bb = g & 7;
  int tid = threadIdx.x;
  const float* Wih = d ? WihB : WihF;
  const float* Whh = d ? WhhB : WhhF;
  const float* bias = d ? bB : bF;

  // stage W slices: rows c = col' (gate*32+jj), 32 chunks of 8 k each
#pragma unroll
  for (int i = 0; i < 8; ++i) {
    int cid = tid + i * 512;
    int c = cid >> 5, kc = cid & 31;
    int nat = (c >> 5) * 256 + hb * 32 + (c & 31);  // weight row (gate*256 + unit)
    int idx = c * 32 + (kc ^ (c & 7));
    const float* si = Wih + (size_t)nat * E_ + kc * 8;
    ((short8*)WiL)[idx] = cvt8(((const f32x4*)si)[0], ((const f32x4*)si)[1]);
    const float* sh = Whh + (size_t)nat * H_ + kc * 8;
    ((short8*)WhL)[idx] = cvt8(((const f32x4*)sh)[0], ((const f32x4*)sh)[1]);
  }

  int w = tid >> 6, l = tid & 63;
  int l15 = l & 15, l4 = l >> 4;
  int sr = tid >> 5, sc = tid & 31;  // stage row (batch 0..15) / chunk (0..31)
  int eb = sr, ej = sc;              // elementwise: batch, unit-in-block

  float bi = bias[hb * 32 + ej];
  float bf_ = bias[256 + hb * 32 + ej];
  float bg = bias[512 + hb * 32 + ej];
  float bo = bias[768 + hb * 32 + ej];

  unsigned short* Hgrp = Hbuf + (size_t)g * 2 * (BB * 256);  // [parity][16][256]
  unsigned* cnt = flags + g * 64;
  float cst = 0.f, hsr = 0.f;

  int brow = w * 16 + l15;            // gate-col 0..127
  int bsw = brow & 7;

  __syncthreads();  // W staged

  for (int t = 0; t < T_; ++t) {
    int t_src = d ? (T_ - 1 - t) : t;
    // stage x_t (masked) -> bf16 swizzled
    {
      int gb = bb * BB + sr;  // global batch
      const float* src = x + ((size_t)gb * T_ + t_src) * E_ + sc * 8;
      float m = mask[(size_t)gb * T_ + t_src];
      f32x4 v0 = ((const f32x4*)src)[0];
      f32x4 v1 = ((const f32x4*)src)[1];
      v0 *= m; v1 *= m;
      ((short8*)XS)[sr * 32 + (sc ^ (sr & 7))] = cvt8(v0, v1);
    }
    if (t > 0) {
      const unsigned short* hsrc = Hgrp + (size_t)(t & 1) * (BB * 256);
      short8 v = *(const short8*)(hsrc + sr * 256 + sc * 8);
      ((short8*)HS)[sr * 32 + (sc ^ (sr & 7))] = v;
    }
    __syncthreads();

    f32x4 acc = {0.f, 0.f, 0.f, 0.f};
    if (t > 0) {
#pragma unroll
      for (int kb = 0; kb < 8; ++kb) {
        int ch = kb * 4 + l4;
        short8 ax = ((short8*)XS)[l15 * 32 + (ch ^ (l15 & 7))];
        short8 wi8 = ((short8*)WiL)[brow * 32 + (ch ^ bsw)];
        acc = mfma16(ax, wi8, acc);
        short8 ah = ((short8*)HS)[l15 * 32 + (ch ^ (l15 & 7))];
        short8 wh8 = ((short8*)WhL)[brow * 32 + (ch ^ bsw)];
        acc = mfma16(ah, wh8, acc);
      }
    } else {
#pragma unroll
      for (int kb = 0; kb < 8; ++kb) {
        int ch = kb * 4 + l4;
        short8 ax = ((short8*)XS)[l15 * 32 + (ch ^ (l15 & 7))];
        short8 wi8 = ((short8*)WiL)[brow * 32 + (ch ^ bsw)];
        acc = mfma16(ax, wi8, acc);
      }
    }
    __syncthreads();  // XS/HS reads done (gates overwrite XS region)

    // D layout: row (batch) = l4*4+r, col = brow
#pragma unroll
    for (int r = 0; r < 4; ++r) gatesL[(l4 * 4 + r) * 128 + brow] = acc[r];
    __syncthreads();

    // elementwise LSTM update (fp32); cols of gatesL: gate*32 + unit
    float gi = gatesL[eb * 128 + ej] + bi;
    float gf = gatesL[eb * 128 + 32 + ej] + bf_;
    float gg = gatesL[eb * 128 + 64 + ej] + bg;
    float go = gatesL[eb * 128 + 96 + ej] + bo;
    float c_ = sigmf(gf) * cst + sigmf(gi) * tanhf(gg);
    cst = c_;
    float h_ = sigmf(go) * tanhf(c_);
    hsr += h_;

    if (t + 1 < T_) {
      // publish h_{t+1} slice, then group barrier
      Hgrp[(size_t)((t + 1) & 1) * (BB * 256) + (size_t)eb * 256 + hb * 32 + ej] = f2bf(h_);
      __syncthreads();  // all stores drained (vmcnt 0 at barrier)
      if (tid == 0) {
        __threadfence();  // release: writeback L2 so other XCDs can see h
        __hip_atomic_fetch_add(cnt, 1u, __ATOMIC_RELEASE, __HIP_MEMORY_SCOPE_AGENT);
        unsigned tgt = 8u * (unsigned)(t + 1);
        while (__hip_atomic_load(cnt, __ATOMIC_RELAXED, __HIP_MEMORY_SCOPE_AGENT) < tgt)
          __builtin_amdgcn_s_sleep(4);
        __threadfence();  // acquire: invalidate L1/L2 before reading peers' h
      }
      __syncthreads();
    }
  }

  hsum[(size_t)d * B_ * H_ + (size_t)(bb * BB + eb) * H_ + hb * 32 + ej] = hsr;
}

// ---------------- head: linear ----------------------------------------------
__global__ __launch_bounds__(256, 1) void head_kernel(
    const float* __restrict__ hsum, const float* __restrict__ Wlin,
    const float* __restrict__ blin, float* __restrict__ out) {
  int tid = threadIdx.x;  // 256 = 128 b x 2 c
  int b = tid >> 1, c = tid & 1;
  const f32x4* hf = (const f32x4*)(hsum + (size_t)b * H_);
  const f32x4* hbk = (const f32x4*)(hsum + (size_t)B_ * H_ + (size_t)b * H_);
  const f32x4* wl = (const f32x4*)(Wlin + (size_t)c * 512);
  float s = 0.f;
  for (int j = 0; j < 64; ++j) {
    f32x4 a = hf[j], ww = wl[j];
    s += a[0] * ww[0] + a[1] * ww[1] + a[2] * ww[2] + a[3] * ww[3];
  }
  for (int j = 0; j < 64; ++j) {
    f32x4 a = hbk[j], ww = wl[64 + j];
    s += a[0] * ww[0] + a[1] * ww[1] + a[2] * ww[2] + a[3] * ww[3];
  }
  out[tid] = s * (1.0f / 1024.0f) + blin[c];
}

// ---------------- launch -----------------------------------------------------
extern "C" void kernel_launch(void* const* d_in, const int* in_sizes, int n_in,
                              void* d_out, int out_size, void* d_ws, size_t ws_size,
                              hipStream_t stream) {
  const float* emb = (const float*)d_in[0];
  const float* mask = (const float*)d_in[1];
  const float* Wih_f = (const float*)d_in[2];
  const float* Whh_f = (const float*)d_in[3];
  const float* b_f = (const float*)d_in[4];
  const float* Wih_b = (const float*)d_in[5];
  const float* Whh_b = (const float*)d_in[6];
  const float* b_b = (const float*)d_in[7];
  const float* Wlin = (const float*)d_in[8];
  const float* blin = (const float*)d_in[9];
  float* out = (float*)d_out;

  const size_t HBUF_BYTES = (size_t)NGRP * 2 * (BB * 256) * 2;  // 256 KiB
  const size_t HSUM_BYTES = (size_t)2 * B_ * H_ * 4;            // 256 KiB
  const size_t FLAGS_BYTES = NGRP * 64 * 4;                     // 4 KiB
  if (ws_size < HBUF_BYTES + HSUM_BYTES + FLAGS_BYTES) return;

  char* ws = (char*)d_ws;
  unsigned short* Hbuf = (unsigned short*)ws;
  float* hsum = (float*)(ws + HBUF_BYTES);
  unsigned* flags = (unsigned*)(ws + HBUF_BYTES + HSUM_BYTES);

  hipMemsetAsync(flags, 0, FLAGS_BYTES, stream);
  rec_kernel<<<128, 512, 0, stream>>>(emb, mask, Wih_f, Whh_f, b_f,
                                      Wih_b, Whh_b, b_b, Hbuf, hsum, flags);
  head_kernel<<<1, 256, 0, stream>>>(hsum, Wlin, blin, out);
}

// Round 3
// 2249.241 us; speedup vs baseline: 3.4883x; 3.4883x over previous
//
#include <hip/hip_runtime.h>

// LSTMFromEmbeddings: B=128, T=1024, E=256, H=256, C=2, bidirectional + meanpool + linear.
//
// Latency-optimized design:
//  rec: 64 persistent wgs = 16 groups (2 dir x 8 batch-blocks of 16) x 4 members
//       (64 hidden units each). ALL weights (W_ih + W_hh slices) live in REGISTERS
//       as MFMA B-fragments (128 VGPR/lane). Per step: hh MFMA (h from LDS) ->
//       gates -> fp32 LSTM elementwise -> publish h via device-scope relaxed atomic
//       64b stores with an embedded step TAG (self-synchronizing, no fences, no
//       flag hop, no L2 flushes) -> stage x_{t+1} + compute xg_{t+1} (hides peer
//       latency) -> retry-load peers' tagged words -> stage h into LDS.
//       Parity double-buffer bounds skew (<=2 steps by data dependency).
//  head: out = (hsum/1024) @ W_lin^T + b_lin.

#define B_ 128
#define T_ 1024
#define E_ 256
#define H_ 256

typedef short short8 __attribute__((ext_vector_type(8)));
typedef float f32x4 __attribute__((ext_vector_type(4)));

__device__ __forceinline__ unsigned short f2bf(float f) {
  unsigned u = __builtin_bit_cast(unsigned, f);
  u += 0x7fffu + ((u >> 16) & 1u);  // RNE
  return (unsigned short)(u >> 16);
}
__device__ __forceinline__ f32x4 mfma16(short8 a, short8 b, f32x4 c) {
  return __builtin_amdgcn_mfma_f32_16x16x32_bf16(a, b, c, 0, 0, 0);
}
__device__ __forceinline__ float sigmf(float x) { return 1.0f / (1.0f + __expf(-x)); }
__device__ __forceinline__ float tanhfast(float x) { return 2.0f / (1.0f + __expf(-2.0f * x)) - 1.0f; }

__device__ __forceinline__ short8 cvt8(f32x4 v0, f32x4 v1) {
  short8 o;
  o[0] = (short)f2bf(v0[0]); o[1] = (short)f2bf(v0[1]);
  o[2] = (short)f2bf(v0[2]); o[3] = (short)f2bf(v0[3]);
  o[4] = (short)f2bf(v1[0]); o[5] = (short)f2bf(v1[1]);
  o[6] = (short)f2bf(v1[2]); o[7] = (short)f2bf(v1[3]);
  return o;
}

// ---------------- rec: fused projection + recurrence, weights-in-registers ---
// grid 64, 512 threads. group g = bid & 15, member m = bid >> 4 (co-XCD heuristic:
// members' bid%8 identical). Member m owns hidden units [m*64, m*64+64).
__global__ __launch_bounds__(512, 1) void rec_kernel(
    const float* __restrict__ x, const float* __restrict__ mask,
    const float* __restrict__ WihF, const float* __restrict__ WhhF,
    const float* __restrict__ bF, const float* __restrict__ WihB,
    const float* __restrict__ WhhB, const float* __restrict__ bB,
    unsigned long long* __restrict__ Hbuf, float* __restrict__ hsum) {
  __shared__ __align__(16) short XS[16 * 256];     // x_t stage bf16 swizzled (8KB)
  __shared__ __align__(16) short HS[16 * 256];     // h_t stage bf16 swizzled (8KB)
  __shared__ __align__(16) float gatesL[16 * 260]; // gates fp32, +4 pad (16.6KB)

  const int bid = blockIdx.x;
  const int g = bid & 15, m = bid >> 4;
  const int d = g >> 3, bblk = g & 7;
  const int tid = threadIdx.x;
  const int w = tid >> 6, l = tid & 63, l15 = l & 15, l4 = l >> 4;
  const int sr = tid >> 5, sc = tid & 31;  // stage/elementwise: batch row, chunk
  const int ej2 = sc * 2;                  // local unit base (2 units/thread)
  const int gb = bblk * 16 + sr;           // global batch

  const float* Wih = d ? WihB : WihF;
  const float* Whh = d ? WhhB : WhhF;
  const float* bias = d ? bB : bF;

  // ---- weight fragments -> registers (one-time) ----
  // col' = gate*64 + ul (ul = unit local 0..63); wave w owns col-tiles {2w, 2w+1}.
  short8 wi[2][8], wh[2][8];
#pragma unroll
  for (int i = 0; i < 2; ++i) {
    int cp = (2 * w + i) * 16 + l15;
    int gate = cp >> 6, ul = cp & 63;
    size_t nat = (size_t)(gate * 256 + m * 64 + ul);
#pragma unroll
    for (int kb = 0; kb < 8; ++kb) {
      const f32x4* pi = (const f32x4*)(Wih + nat * E_ + kb * 32 + l4 * 8);
      wi[i][kb] = cvt8(pi[0], pi[1]);
      const f32x4* ph = (const f32x4*)(Whh + nat * H_ + kb * 32 + l4 * 8);
      wh[i][kb] = cvt8(ph[0], ph[1]);
    }
  }

  // biases for this thread's 2 units (4 gates each)
  const int ub = m * 64 + ej2;
  float bI0 = bias[ub], bI1 = bias[ub + 1];
  float bF0 = bias[256 + ub], bF1 = bias[256 + ub + 1];
  float bG0 = bias[512 + ub], bG1 = bias[512 + ub + 1];
  float bO0 = bias[768 + ub], bO1 = bias[768 + ub + 1];

  // ---- prologue: stage x_0, acc = xg_0 ----
  {
    int ts = d ? (T_ - 1) : 0;
    const f32x4* px = (const f32x4*)(x + ((size_t)gb * T_ + ts) * E_ + sc * 8);
    float mk = mask[(size_t)gb * T_ + ts];
    f32x4 v0 = px[0] * mk, v1 = px[1] * mk;
    ((short8*)XS)[sr * 32 + (sc ^ (sr & 7))] = cvt8(v0, v1);
  }
  __syncthreads();
  f32x4 acc[2] = {};
#pragma unroll
  for (int kb = 0; kb < 8; ++kb) {
    short8 a = ((short8*)XS)[l15 * 32 + ((kb * 4 + l4) ^ (l15 & 7))];
    acc[0] = mfma16(a, wi[0][kb], acc[0]);
    acc[1] = mfma16(a, wi[1][kb], acc[1]);
  }

  float cs0 = 0.f, cs1 = 0.f, hs0 = 0.f, hs1 = 0.f;

  for (int t = 0; t < T_; ++t) {
    // prefetch x_{t+1} (in flight during MFMA + elementwise)
    f32x4 xv0, xv1;
    float mk = 0.f;
    if (t + 1 < T_) {
      int ts = d ? (T_ - 2 - t) : (t + 1);
      const f32x4* px = (const f32x4*)(x + ((size_t)gb * T_ + ts) * E_ + sc * 8);
      xv0 = px[0];
      xv1 = px[1];
      mk = mask[(size_t)gb * T_ + ts];
    }

    // hh product into acc (acc holds xg_t)
    if (t > 0) {
#pragma unroll
      for (int kb = 0; kb < 8; ++kb) {
        short8 a = ((short8*)HS)[l15 * 32 + ((kb * 4 + l4) ^ (l15 & 7))];
        acc[0] = mfma16(a, wh[0][kb], acc[0]);
        acc[1] = mfma16(a, wh[1][kb], acc[1]);
      }
    }

    // gates -> LDS. D layout: row(batch)=l4*4+r, col'=(2w+i)*16+l15
#pragma unroll
    for (int i = 0; i < 2; ++i)
#pragma unroll
      for (int r = 0; r < 4; ++r)
        gatesL[(l4 * 4 + r) * 260 + (2 * w + i) * 16 + l15] = acc[i][r];
    __syncthreads();

    // fp32 LSTM elementwise: 2 units (ej2, ej2+1), batch sr
    float gi0 = gatesL[sr * 260 + ej2] + bI0;
    float gf0 = gatesL[sr * 260 + 64 + ej2] + bF0;
    float gg0 = gatesL[sr * 260 + 128 + ej2] + bG0;
    float go0 = gatesL[sr * 260 + 192 + ej2] + bO0;
    float gi1 = gatesL[sr * 260 + ej2 + 1] + bI1;
    float gf1 = gatesL[sr * 260 + 64 + ej2 + 1] + bF1;
    float gg1 = gatesL[sr * 260 + 128 + ej2 + 1] + bG1;
    float go1 = gatesL[sr * 260 + 192 + ej2 + 1] + bO1;
    cs0 = sigmf(gf0) * cs0 + sigmf(gi0) * tanhfast(gg0);
    cs1 = sigmf(gf1) * cs1 + sigmf(gi1) * tanhfast(gg1);
    float h0 = sigmf(go0) * tanhfast(cs0);
    float h1 = sigmf(go1) * tanhfast(cs1);
    hs0 += h0;
    hs1 += h1;

    if (t + 1 < T_) {
      unsigned tag = (unsigned)(t + 1);
      size_t base = ((size_t)g * 2 + (tag & 1)) * 16;  // [group][parity][batch][128 words]

      // publish: tagged 64b word = [tag:32][h1:16][h0:16], fire-and-forget
      unsigned payload = (unsigned)f2bf(h0) | ((unsigned)f2bf(h1) << 16);
      unsigned long long word = (((unsigned long long)tag) << 32) | payload;
      __hip_atomic_store(&Hbuf[(base + sr) * 128 + m * 32 + sc], word,
                         __ATOMIC_RELAXED, __HIP_MEMORY_SCOPE_AGENT);

      // stage x_{t+1} (local work hides peer store latency)
      ((short8*)XS)[sr * 32 + (sc ^ (sr & 7))] = cvt8(xv0 * mk, xv1 * mk);
      __syncthreads();

      // acc = xg_{t+1}
      acc[0] = (f32x4){0.f, 0.f, 0.f, 0.f};
      acc[1] = (f32x4){0.f, 0.f, 0.f, 0.f};
#pragma unroll
      for (int kb = 0; kb < 8; ++kb) {
        short8 a = ((short8*)XS)[l15 * 32 + ((kb * 4 + l4) ^ (l15 & 7))];
        acc[0] = mfma16(a, wi[0][kb], acc[0]);
        acc[1] = mfma16(a, wi[1][kb], acc[1]);
      }

      // poll peers' h_{t+1}: thread needs units sc*8..sc*8+7 for batch sr
      const unsigned long long* rp = &Hbuf[(base + sr) * 128 + sc * 4];
      unsigned long long vv[4];
#pragma unroll
      for (int j = 0; j < 4; ++j)
        vv[j] = __hip_atomic_load(&rp[j], __ATOMIC_RELAXED, __HIP_MEMORY_SCOPE_AGENT);
#pragma unroll
      for (int j = 0; j < 4; ++j)
        while ((unsigned)(vv[j] >> 32) != tag)
          vv[j] = __hip_atomic_load(&rp[j], __ATOMIC_RELAXED, __HIP_MEMORY_SCOPE_AGENT);
      short8 hv;
#pragma unroll
      for (int j = 0; j < 4; ++j) {
        hv[2 * j] = (short)(unsigned short)(vv[j] & 0xffffu);
        hv[2 * j + 1] = (short)(unsigned short)((vv[j] >> 16) & 0xffffu);
      }
      ((short8*)HS)[sr * 32 + (sc ^ (sr & 7))] = hv;
      __syncthreads();
    }
  }

  // pooled sums (disjoint slots)
  hsum[((size_t)d * B_ + gb) * H_ + ub] = hs0;
  hsum[((size_t)d * B_ + gb) * H_ + ub + 1] = hs1;
}

// ---------------- head: linear ----------------------------------------------
__global__ __launch_bounds__(256, 1) void head_kernel(
    const float* __restrict__ hsum, const float* __restrict__ Wlin,
    const float* __restrict__ blin, float* __restrict__ out) {
  int tid = threadIdx.x;  // 256 = 128 b x 2 c
  int b = tid >> 1, c = tid & 1;
  const f32x4* hf = (const f32x4*)(hsum + (size_t)b * H_);
  const f32x4* hbk = (const f32x4*)(hsum + (size_t)B_ * H_ + (size_t)b * H_);
  const f32x4* wl = (const f32x4*)(Wlin + (size_t)c * 512);
  float s = 0.f;
  for (int j = 0; j < 64; ++j) {
    f32x4 a = hf[j], ww = wl[j];
    s += a[0] * ww[0] + a[1] * ww[1] + a[2] * ww[2] + a[3] * ww[3];
  }
  for (int j = 0; j < 64; ++j) {
    f32x4 a = hbk[j], ww = wl[64 + j];
    s += a[0] * ww[0] + a[1] * ww[1] + a[2] * ww[2] + a[3] * ww[3];
  }
  out[tid] = s * (1.0f / 1024.0f) + blin[c];
}

// ---------------- launch -----------------------------------------------------
extern "C" void kernel_launch(void* const* d_in, const int* in_sizes, int n_in,
                              void* d_out, int out_size, void* d_ws, size_t ws_size,
                              hipStream_t stream) {
  const float* emb = (const float*)d_in[0];
  const float* mask = (const float*)d_in[1];
  const float* Wih_f = (const float*)d_in[2];
  const float* Whh_f = (const float*)d_in[3];
  const float* b_f = (const float*)d_in[4];
  const float* Wih_b = (const float*)d_in[5];
  const float* Whh_b = (const float*)d_in[6];
  const float* b_b = (const float*)d_in[7];
  const float* Wlin = (const float*)d_in[8];
  const float* blin = (const float*)d_in[9];
  float* out = (float*)d_out;

  // Hbuf: [16 groups][2 parity][16 batches][128 unit-pair words] x 8B = 512 KiB
  const size_t HBUF_BYTES = (size_t)16 * 2 * 16 * 128 * 8;
  const size_t HSUM_BYTES = (size_t)2 * B_ * H_ * 4;  // 256 KiB
  if (ws_size < HBUF_BYTES + HSUM_BYTES) return;

  char* ws = (char*)d_ws;
  unsigned long long* Hbuf = (unsigned long long*)ws;
  float* hsum = (float*)(ws + HBUF_BYTES);

  hipMemsetAsync(Hbuf, 0, HBUF_BYTES, stream);  // zero tags (tags start at 1)
  rec_kernel<<<64, 512, 0, stream>>>(emb, mask, Wih_f, Whh_f, b_f,
                                     Wih_b, Whh_b, b_b, Hbuf, hsum);
  head_kernel<<<1, 256, 0, stream>>>(hsum, Wlin, blin, out);
}